// Round 1
// baseline (193.503 us; speedup 1.0000x reference)
//
#include <hip/hip_runtime.h>
#include <cstdint>
#include <cstddef>

#define N_NODES 50000
#define N_EDGES 640000
#define DF 128

#define NBUCK 196          // buckets of 256 nodes: bucket = dst >> 8
#define BCAP  6144         // staging capacity per bucket (mean 3265, +50 sigma)
#define PA_BLOCKS 250      // PassA blocks, 2560 edges each (250*2560 = 640000)

typedef __attribute__((ext_vector_type(8))) short bf16x8;
typedef __attribute__((ext_vector_type(4))) float f32x4;

__device__ inline unsigned short f2bf(float f) {            // RNE float->bf16
    unsigned int u = __float_as_uint(f);
    return (unsigned short)((u + 0x7fffu + ((u >> 16) & 1u)) >> 16);
}

// ================= K1: PassA (coarse bucket sort) || setup ===================
// blocks [0,250):        PassA — bin 2560 edges into 196 coarse buckets.
//   LDS count -> one global atomic per (block,bucket) reserves a contiguous
//   run -> packed 8B records {src|dstlocal<<16, w} stored in ~100B runs.
// blocks [250,6500):     featb = bf16(feat)
// blocks [6500,6524):    W fragments (B-operand order for 16x16x32 MFMA)
#define NF4 (N_NODES * DF / 4)        // 1,600,000
#define NWG (3 * 2048)
__global__ __launch_bounds__(256) void k1_setup_bucket(
    const float* __restrict__ feat,
    const float* __restrict__ W_pool,
    const float* __restrict__ W_neigh,
    const int* __restrict__ src,
    const int* __restrict__ dst,
    const float* __restrict__ w,
    unsigned short* __restrict__ featb,
    unsigned short* __restrict__ Wp_f,
    unsigned short* __restrict__ Wn1_f,
    unsigned short* __restrict__ Wn2_f,
    int* __restrict__ bucketcnt,        // pre-zeroed via hipMemsetAsync
    uint2* __restrict__ staging)
{
    int bid = blockIdx.x;
    int t = threadIdx.x;
    if (bid < PA_BLOCKS) {
        __shared__ int cnt[NBUCK];
        __shared__ int runbase[NBUCK];
        int base = bid * 2560;
        if (t < NBUCK) cnt[t] = 0;
        __syncthreads();
        uint2 rec[10];
        int bk[10];
        #pragma unroll
        for (int i = 0; i < 10; ++i) {
            int e = base + i * 256 + t;
            int s = src[e], d = dst[e];
            bk[i] = d >> 8;
            rec[i].x = (unsigned int)s | ((unsigned int)(d & 255) << 16);
            rec[i].y = __float_as_uint(w[e]);
            atomicAdd(&cnt[bk[i]], 1);
        }
        __syncthreads();
        if (t < NBUCK) {
            runbase[t] = atomicAdd(&bucketcnt[t], cnt[t]);
            cnt[t] = 0;                 // reuse as within-run cursor
        }
        __syncthreads();
        #pragma unroll
        for (int i = 0; i < 10; ++i) {
            int r = atomicAdd(&cnt[bk[i]], 1);
            int pos = runbase[bk[i]] + r;
            if (pos < BCAP) staging[bk[i] * BCAP + pos] = rec[i];
        }
    } else if (bid < 250 + NF4 / 256) {
        int idx = (bid - PA_BLOCKS) * 256 + t;
        float4 v = ((const float4*)feat)[idx];
        ushort4 o;
        o.x = f2bf(v.x); o.y = f2bf(v.y); o.z = f2bf(v.z); o.w = f2bf(v.w);
        ((ushort4*)featb)[idx] = o;
    } else {
        int g = (bid - PA_BLOCKS - NF4 / 256) * 256 + t;   // < NWG
        int m = g >> 11;
        int r8 = g & 2047;          // (c*4+tt)*64 + L
        int L = r8 & 63, tt = (r8 >> 6) & 3, c = r8 >> 8;
        int o = c * 16 + (L & 15);
        int kb = tt * 32 + (L >> 4) * 8;
        const float* srcp;
        unsigned short* dstp;
        if (m == 0)      { srcp = W_pool  + o * 128 + kb;       dstp = Wp_f;  }
        else if (m == 1) { srcp = W_neigh + o * 256 + kb;       dstp = Wn1_f; }
        else             { srcp = W_neigh + o * 256 + 128 + kb; dstp = Wn2_f; }
        ushort4 lo, hi;
        float4 a = ((const float4*)srcp)[0];
        float4 b = ((const float4*)srcp)[1];
        lo.x = f2bf(a.x); lo.y = f2bf(a.y); lo.z = f2bf(a.z); lo.w = f2bf(a.w);
        hi.x = f2bf(b.x); hi.y = f2bf(b.y); hi.z = f2bf(b.z); hi.w = f2bf(b.w);
        ((ushort4*)(dstp + r8 * 8))[0] = lo;
        ((ushort4*)(dstp + r8 * 8))[1] = hi;
    }
}

// ================= K2: gemm_pool || PassB (per-bucket fine sort) =============
// blocks [0,196):  gemm_pool — hb = bf16(featb @ Wp^T + b_pool), 16 waves/blk
// blocks [196,392): PassB — bucket b: base = prefix(bucketcnt), count+scan
//   per-node degrees in LDS, write offsets, re-scatter records into final
//   dst-sorted edges[] (stores confined to this block's ~26KB region).
#define GEMMB 196          // ceil(3125 waves / 16)
__global__ __launch_bounds__(1024) void k2_gemm_passb(
    const unsigned short* __restrict__ featb,
    const unsigned short* __restrict__ Wp_f,
    const float* __restrict__ b_pool,
    unsigned short* __restrict__ hb,
    const int* __restrict__ bucketcnt,
    const uint2* __restrict__ staging,
    int* __restrict__ offsets,
    uint2* __restrict__ edges)
{
    int t = threadIdx.x;
    if (blockIdx.x < GEMMB) {
        int wave = blockIdx.x * 16 + (t >> 6);
        int lane = t & 63;
        int m0 = wave * 16;
        if (m0 >= N_NODES) return;          // no barriers on this path
        const int n = lane & 15, quad = lane >> 4;

        f32x4 acc[8];
        #pragma unroll
        for (int c = 0; c < 8; ++c) {
            float bv = b_pool[c * 16 + n];
            acc[c] = (f32x4){bv, bv, bv, bv};
        }
        const unsigned short* aptr = featb + (size_t)(m0 + n) * DF + quad * 8;
        #pragma unroll
        for (int tt = 0; tt < 4; ++tt) {
            bf16x8 af = *(const bf16x8*)(aptr + tt * 32);
            #pragma unroll
            for (int c = 0; c < 8; ++c) {
                bf16x8 bf = *(const bf16x8*)(Wp_f + (size_t)((c * 4 + tt) * 64 + lane) * 8);
                acc[c] = __builtin_amdgcn_mfma_f32_16x16x32_bf16(af, bf, acc[c], 0, 0, 0);
            }
        }
        #pragma unroll
        for (int c = 0; c < 8; ++c)
            #pragma unroll
            for (int r = 0; r < 4; ++r)
                hb[(size_t)(m0 + quad * 4 + r) * DF + c * 16 + n] = f2bf(acc[c][r]);
    } else {
        __shared__ int dcnt[256];       // per-node count, then global cursor
        __shared__ int sc[256];         // scan scratch
        __shared__ int bc[256];         // bucket counts
        int b = blockIdx.x - GEMMB;     // 0..195

        if (t < 256) { dcnt[t] = 0; bc[t] = (t < NBUCK) ? bucketcnt[t] : 0; sc[t] = (t < NBUCK) ? bc[t] : 0; }
        __syncthreads();
        // exclusive prefix of bucket counts (Hillis-Steele over 256)
        #pragma unroll
        for (int off = 1; off < 256; off <<= 1) {
            int u = (t < 256 && t >= off) ? sc[t - off] : 0;
            __syncthreads();
            if (t < 256) sc[t] += u;
            __syncthreads();
        }
        int mybase = (b > 0) ? sc[b - 1] : 0;
        int cnt = bc[b];
        __syncthreads();                 // sc about to be reused

        // load my staged records, count per-node degrees
        uint2 rec[6];
        int nit = (cnt + 1023) >> 10;
        for (int i = 0; i < nit; ++i) {
            int idx = i * 1024 + t;
            if (idx < cnt) {
                rec[i] = staging[(size_t)b * BCAP + idx];
                atomicAdd(&dcnt[(rec[i].x >> 16) & 255], 1);
            }
        }
        __syncthreads();
        if (t < 256) sc[t] = dcnt[t];
        __syncthreads();
        #pragma unroll
        for (int off = 1; off < 256; off <<= 1) {
            int u = (t < 256 && t >= off) ? sc[t - off] : 0;
            __syncthreads();
            if (t < 256) sc[t] += u;
            __syncthreads();
        }
        if (t < 256) {
            int node = b * 256 + t;
            int excl = sc[t] - dcnt[t];
            if (node < N_NODES) offsets[node] = mybase + excl;
            dcnt[t] = mybase + excl;     // repurpose: global write cursor
        }
        if (b == NBUCK - 1 && t == 0) offsets[N_NODES] = mybase + cnt;
        __syncthreads();
        for (int i = 0; i < nit; ++i) {
            int idx = i * 1024 + t;
            if (idx < cnt) {
                int dl = (rec[i].x >> 16) & 255;
                int pos = atomicAdd(&dcnt[dl], 1);
                uint2 fin;
                fin.x = rec[i].x & 0xFFFFu;     // src
                fin.y = rec[i].y;               // w bits
                edges[pos] = fin;
            }
        }
    }
}

// ========== K3fused: per-node max over incoming messages + output GEMM ======
// One block = one 16-row output tile (50000/16 = 3125 blocks, exact).
// Phase 1 (per wave, 4 nodes serial): the verified 8-edge gather loop from
//   the old K3 (R9: keep low-VGPR 8-edge form — L3-BW-bound, not latency).
//   Reduced rows -> 4KB LDS tile, XOR-swizzled by (row&7)<<4 so the MFMA
//   A-fragment ds_read_b128 at 256B row stride doesn't 16-way bank-conflict
//   (swizzle applied on BOTH write and read sides — same involution).
// Phase 2a (pre-barrier): featb @ Wn1^T — global operands only, so waves
//   that finish their gather early absorb block-internal degree imbalance
//   with MFMA work instead of idling at the barrier.
// Phase 2b (post-barrier): neigh @ Wn2^T from LDS, then f32 store.
// Eliminates the neighb global round-trip (25.6 MB) and one launch boundary.
__global__ __launch_bounds__(256) void fused_max_out(
    const unsigned short* __restrict__ featb,
    const unsigned short* __restrict__ hb,
    const int* __restrict__ offsets,
    const uint2* __restrict__ edges,
    const unsigned short* __restrict__ Wn1_f,
    const unsigned short* __restrict__ Wn2_f,
    const float* __restrict__ bias,
    float* __restrict__ out)
{
    __shared__ __align__(16) unsigned short nsh[16 * DF];   // swizzled 16x128 bf16
    const int t = threadIdx.x;
    const int lane = t & 63;
    const int m0 = blockIdx.x * 16;
    const int half = lane >> 5;      // 0: even edge of pair, 1: odd edge
    const int q = lane & 31;         // column quarter: cols 4q..4q+3

    #pragma unroll 1
    for (int j = 0; j < 4; ++j) {
        const int row = ((t >> 6) << 2) + j;                     // 0..15, wave-uniform
        const int node = __builtin_amdgcn_readfirstlane(m0 + row);
        int beg = offsets[node], end = offsets[node + 1];
        float4 mx = make_float4(-3.4e38f, -3.4e38f, -3.4e38f, -3.4e38f);

        for (int e = beg; e < end; e += 8) {
            int i1 = min(e + 1, end - 1);
            int i2 = min(e + 2, end - 1);
            int i3 = min(e + 3, end - 1);
            int i4 = min(e + 4, end - 1);
            int i5 = min(e + 5, end - 1);
            int i6 = min(e + 6, end - 1);
            int i7 = min(e + 7, end - 1);
            uint2 e0 = edges[e],  e1 = edges[i1], e2 = edges[i2], e3 = edges[i3];
            uint2 e4 = edges[i4], e5 = edges[i5], e6 = edges[i6], e7 = edges[i7];
            uint2 mA = half ? e1 : e0;
            uint2 mB = half ? e3 : e2;
            uint2 mC = half ? e5 : e4;
            uint2 mD = half ? e7 : e6;
            float wA = __uint_as_float(mA.y);
            float wB = __uint_as_float(mB.y);
            float wC = __uint_as_float(mC.y);
            float wD = __uint_as_float(mD.y);
            uint2 pA = *(const uint2*)(hb + (size_t)mA.x * DF + q * 4);
            uint2 pB = *(const uint2*)(hb + (size_t)mB.x * DF + q * 4);
            uint2 pC = *(const uint2*)(hb + (size_t)mC.x * DF + q * 4);
            uint2 pD = *(const uint2*)(hb + (size_t)mD.x * DF + q * 4);
            mx.x = fmaxf(mx.x, __uint_as_float(pA.x << 16)          * wA);
            mx.y = fmaxf(mx.y, __uint_as_float(pA.x & 0xffff0000u)  * wA);
            mx.z = fmaxf(mx.z, __uint_as_float(pA.y << 16)          * wA);
            mx.w = fmaxf(mx.w, __uint_as_float(pA.y & 0xffff0000u)  * wA);
            mx.x = fmaxf(mx.x, __uint_as_float(pB.x << 16)          * wB);
            mx.y = fmaxf(mx.y, __uint_as_float(pB.x & 0xffff0000u)  * wB);
            mx.z = fmaxf(mx.z, __uint_as_float(pB.y << 16)          * wB);
            mx.w = fmaxf(mx.w, __uint_as_float(pB.y & 0xffff0000u)  * wB);
            mx.x = fmaxf(mx.x, __uint_as_float(pC.x << 16)          * wC);
            mx.y = fmaxf(mx.y, __uint_as_float(pC.x & 0xffff0000u)  * wC);
            mx.z = fmaxf(mx.z, __uint_as_float(pC.y << 16)          * wC);
            mx.w = fmaxf(mx.w, __uint_as_float(pC.y & 0xffff0000u)  * wC);
            mx.x = fmaxf(mx.x, __uint_as_float(pD.x << 16)          * wD);
            mx.y = fmaxf(mx.y, __uint_as_float(pD.x & 0xffff0000u)  * wD);
            mx.z = fmaxf(mx.z, __uint_as_float(pD.y << 16)          * wD);
            mx.w = fmaxf(mx.w, __uint_as_float(pD.y & 0xffff0000u)  * wD);
        }

        float4 o;
        o.x = fmaxf(mx.x, __shfl_xor(mx.x, 32));
        o.y = fmaxf(mx.y, __shfl_xor(mx.y, 32));
        o.z = fmaxf(mx.z, __shfl_xor(mx.z, 32));
        o.w = fmaxf(mx.w, __shfl_xor(mx.w, 32));
        if (beg == end) o = make_float4(0.f, 0.f, 0.f, 0.f);
        if (half == 0) {
            ushort4 ob;
            ob.x = f2bf(o.x); ob.y = f2bf(o.y); ob.z = f2bf(o.z); ob.w = f2bf(o.w);
            int boff = row * 256 + ((q * 8) ^ ((row & 7) << 4));   // 8B-aligned
            *(ushort4*)((char*)nsh + boff) = ob;
        }
    }

    // -------- phase 2: out tile = featb@Wn1^T + nsh@Wn2^T + bias ------------
    const int n = lane & 15, quad = lane >> 4;
    f32x4 acc[8];
    #pragma unroll
    for (int c = 0; c < 8; ++c) {
        float bv = bias[c * 16 + n];
        acc[c] = (f32x4){bv, bv, bv, bv};
    }

    const unsigned short* a0 = featb + (size_t)(m0 + n) * DF + quad * 8;
    #pragma unroll
    for (int tt = 0; tt < 4; ++tt) {
        bf16x8 af = *(const bf16x8*)(a0 + tt * 32);
        #pragma unroll
        for (int c = 0; c < 8; ++c) {
            bf16x8 bfv = *(const bf16x8*)(Wn1_f + (size_t)((c * 4 + tt) * 64 + lane) * 8);
            acc[c] = __builtin_amdgcn_mfma_f32_16x16x32_bf16(af, bfv, acc[c], 0, 0, 0);
        }
    }

    __syncthreads();                     // nsh fully written by all waves

    #pragma unroll
    for (int tt = 0; tt < 4; ++tt) {
        int boff = (quad * 16 + tt * 64) ^ ((n & 7) << 4);         // 16B-aligned
        bf16x8 af = *(const bf16x8*)((const char*)nsh + n * 256 + boff);
        #pragma unroll
        for (int c = 0; c < 8; ++c) {
            bf16x8 bfv = *(const bf16x8*)(Wn2_f + (size_t)((c * 4 + tt) * 64 + lane) * 8);
            acc[c] = __builtin_amdgcn_mfma_f32_16x16x32_bf16(af, bfv, acc[c], 0, 0, 0);
        }
    }

    #pragma unroll
    for (int c = 0; c < 8; ++c)
        #pragma unroll
        for (int r = 0; r < 4; ++r)
            out[(size_t)(m0 + quad * 4 + r) * DF + c * 16 + n] = acc[c][r];
}

extern "C" void kernel_launch(void* const* d_in, const int* in_sizes, int n_in,
                              void* d_out, int out_size, void* d_ws, size_t ws_size,
                              hipStream_t stream) {
    const float* feat    = (const float*)d_in[0];
    const float* weight  = (const float*)d_in[1];
    const int*   src     = (const int*)d_in[2];
    const int*   dst     = (const int*)d_in[3];
    const float* W_pool  = (const float*)d_in[4];
    const float* b_pool  = (const float*)d_in[5];
    const float* W_neigh = (const float*)d_in[6];
    const float* b_neigh = (const float*)d_in[7];
    float* out = (float*)d_out;

    char* ws = (char*)d_ws;
    unsigned short* featb  = (unsigned short*)(ws);              // 12,800,000 B
    unsigned short* hb     = (unsigned short*)(ws + 12800000);   // 12,800,000 B
    // (ws + 25600000 .. 38400000 formerly neighb — now unused after K3/K4 fusion)
    unsigned short* Wp_f   = (unsigned short*)(ws + 38400000);   // 32,768 B
    unsigned short* Wn1_f  = (unsigned short*)(ws + 38432768);   // 32,768 B
    unsigned short* Wn2_f  = (unsigned short*)(ws + 38465536);   // 32,768 B
    int*   offsets   = (int*)  (ws + 38498304);                  // 200,064 B
    int*   bucketcnt = (int*)  (ws + 38698368);                  // 1,024 B
    uint2* staging   = (uint2*)(ws + 38699392);                  // 9,633,792 B
    uint2* edges     = (uint2*)(ws + 48333184);                  // 5,120,000 B -> ~53.5 MB

    hipMemsetAsync(bucketcnt, 0, 1024, stream);

    // K1: PassA (coarse bucket scatter) || featb conversion || W fragments
    const int K1_BLOCKS = PA_BLOCKS + NF4 / 256 + NWG / 256;   // 250+6250+24
    k1_setup_bucket<<<K1_BLOCKS, 256, 0, stream>>>(
        feat, W_pool, W_neigh, src, dst, weight,
        featb, Wp_f, Wn1_f, Wn2_f, bucketcnt, staging);

    // K2: gemm_pool (hb) || PassB (offsets + final dst-sorted edges)
    k2_gemm_passb<<<GEMMB + NBUCK, 1024, 0, stream>>>(
        featb, Wp_f, b_pool, hb, bucketcnt, staging, offsets, edges);

    // K3fused: segment-max gather + out = featb@Wn1^T + neigh@Wn2^T + b_neigh
    fused_max_out<<<N_NODES / 16, 256, 0, stream>>>(
        featb, hb, offsets, edges, Wn1_f, Wn2_f, b_neigh, out);
}

// Round 2
// 163.380 us; speedup vs baseline: 1.1844x; 1.1844x over previous
//
#include <hip/hip_runtime.h>
#include <cstdint>
#include <cstddef>

#define N_NODES 50000
#define N_EDGES 640000
#define DF 128

#define NBUCK 196          // buckets of 256 nodes: bucket = dst >> 8
#define BCAP  6144         // staging capacity per bucket (mean 3265, +50 sigma)
#define PA_BLOCKS 250      // PassA blocks, 2560 edges each (250*2560 = 640000)

typedef __attribute__((ext_vector_type(8))) short bf16x8;
typedef __attribute__((ext_vector_type(4))) float f32x4;

__device__ inline unsigned short f2bf(float f) {            // RNE float->bf16
    unsigned int u = __float_as_uint(f);
    return (unsigned short)((u + 0x7fffu + ((u >> 16) & 1u)) >> 16);
}

// ================= K1: PassA (coarse bucket sort) || setup ===================
// blocks [0,250):        PassA — bin 2560 edges into 196 coarse buckets.
//   LDS count -> one global atomic per (block,bucket) reserves a contiguous
//   run -> packed 8B records {src|dstlocal<<16, w} stored in ~100B runs.
// blocks [250,6500):     featb = bf16(feat)
// blocks [6500,6524):    W fragments (B-operand order for 16x16x32 MFMA)
#define NF4 (N_NODES * DF / 4)        // 1,600,000
#define NWG (3 * 2048)
__global__ __launch_bounds__(256) void k1_setup_bucket(
    const float* __restrict__ feat,
    const float* __restrict__ W_pool,
    const float* __restrict__ W_neigh,
    const int* __restrict__ src,
    const int* __restrict__ dst,
    const float* __restrict__ w,
    unsigned short* __restrict__ featb,
    unsigned short* __restrict__ Wp_f,
    unsigned short* __restrict__ Wn1_f,
    unsigned short* __restrict__ Wn2_f,
    int* __restrict__ bucketcnt,        // pre-zeroed via hipMemsetAsync
    uint2* __restrict__ staging)
{
    int bid = blockIdx.x;
    int t = threadIdx.x;
    if (bid < PA_BLOCKS) {
        __shared__ int cnt[NBUCK];
        __shared__ int runbase[NBUCK];
        int base = bid * 2560;
        if (t < NBUCK) cnt[t] = 0;
        __syncthreads();
        uint2 rec[10];
        int bk[10];
        #pragma unroll
        for (int i = 0; i < 10; ++i) {
            int e = base + i * 256 + t;
            int s = src[e], d = dst[e];
            bk[i] = d >> 8;
            rec[i].x = (unsigned int)s | ((unsigned int)(d & 255) << 16);
            rec[i].y = __float_as_uint(w[e]);
            atomicAdd(&cnt[bk[i]], 1);
        }
        __syncthreads();
        if (t < NBUCK) {
            runbase[t] = atomicAdd(&bucketcnt[t], cnt[t]);
            cnt[t] = 0;                 // reuse as within-run cursor
        }
        __syncthreads();
        #pragma unroll
        for (int i = 0; i < 10; ++i) {
            int r = atomicAdd(&cnt[bk[i]], 1);
            int pos = runbase[bk[i]] + r;
            if (pos < BCAP) staging[bk[i] * BCAP + pos] = rec[i];
        }
    } else if (bid < 250 + NF4 / 256) {
        int idx = (bid - PA_BLOCKS) * 256 + t;
        float4 v = ((const float4*)feat)[idx];
        ushort4 o;
        o.x = f2bf(v.x); o.y = f2bf(v.y); o.z = f2bf(v.z); o.w = f2bf(v.w);
        ((ushort4*)featb)[idx] = o;
    } else {
        int g = (bid - PA_BLOCKS - NF4 / 256) * 256 + t;   // < NWG
        int m = g >> 11;
        int r8 = g & 2047;          // (c*4+tt)*64 + L
        int L = r8 & 63, tt = (r8 >> 6) & 3, c = r8 >> 8;
        int o = c * 16 + (L & 15);
        int kb = tt * 32 + (L >> 4) * 8;
        const float* srcp;
        unsigned short* dstp;
        if (m == 0)      { srcp = W_pool  + o * 128 + kb;       dstp = Wp_f;  }
        else if (m == 1) { srcp = W_neigh + o * 256 + kb;       dstp = Wn1_f; }
        else             { srcp = W_neigh + o * 256 + 128 + kb; dstp = Wn2_f; }
        ushort4 lo, hi;
        float4 a = ((const float4*)srcp)[0];
        float4 b = ((const float4*)srcp)[1];
        lo.x = f2bf(a.x); lo.y = f2bf(a.y); lo.z = f2bf(a.z); lo.w = f2bf(a.w);
        hi.x = f2bf(b.x); hi.y = f2bf(b.y); hi.z = f2bf(b.z); hi.w = f2bf(b.w);
        ((ushort4*)(dstp + r8 * 8))[0] = lo;
        ((ushort4*)(dstp + r8 * 8))[1] = hi;
    }
}

// ================= K2: gemm_pool || PassB (per-bucket fine sort) =============
// blocks [0,196):  gemm_pool — hb = bf16(featb @ Wp^T + b_pool), 16 waves/blk
// blocks [196,392): PassB — bucket b: base = prefix(bucketcnt), count+scan
//   per-node degrees in LDS, write offsets, re-scatter records into final
//   dst-sorted edges[] (stores confined to this block's ~26KB region).
#define GEMMB 196          // ceil(3125 waves / 16)
__global__ __launch_bounds__(1024) void k2_gemm_passb(
    const unsigned short* __restrict__ featb,
    const unsigned short* __restrict__ Wp_f,
    const float* __restrict__ b_pool,
    unsigned short* __restrict__ hb,
    const int* __restrict__ bucketcnt,
    const uint2* __restrict__ staging,
    int* __restrict__ offsets,
    uint2* __restrict__ edges)
{
    int t = threadIdx.x;
    if (blockIdx.x < GEMMB) {
        int wave = blockIdx.x * 16 + (t >> 6);
        int lane = t & 63;
        int m0 = wave * 16;
        if (m0 >= N_NODES) return;          // no barriers on this path
        const int n = lane & 15, quad = lane >> 4;

        f32x4 acc[8];
        #pragma unroll
        for (int c = 0; c < 8; ++c) {
            float bv = b_pool[c * 16 + n];
            acc[c] = (f32x4){bv, bv, bv, bv};
        }
        const unsigned short* aptr = featb + (size_t)(m0 + n) * DF + quad * 8;
        #pragma unroll
        for (int tt = 0; tt < 4; ++tt) {
            bf16x8 af = *(const bf16x8*)(aptr + tt * 32);
            #pragma unroll
            for (int c = 0; c < 8; ++c) {
                bf16x8 bf = *(const bf16x8*)(Wp_f + (size_t)((c * 4 + tt) * 64 + lane) * 8);
                acc[c] = __builtin_amdgcn_mfma_f32_16x16x32_bf16(af, bf, acc[c], 0, 0, 0);
            }
        }
        #pragma unroll
        for (int c = 0; c < 8; ++c)
            #pragma unroll
            for (int r = 0; r < 4; ++r)
                hb[(size_t)(m0 + quad * 4 + r) * DF + c * 16 + n] = f2bf(acc[c][r]);
    } else {
        __shared__ int dcnt[256];       // per-node count, then global cursor
        __shared__ int sc[256];         // scan scratch
        __shared__ int bc[256];         // bucket counts
        int b = blockIdx.x - GEMMB;     // 0..195

        if (t < 256) { dcnt[t] = 0; bc[t] = (t < NBUCK) ? bucketcnt[t] : 0; sc[t] = (t < NBUCK) ? bc[t] : 0; }
        __syncthreads();
        // exclusive prefix of bucket counts (Hillis-Steele over 256)
        #pragma unroll
        for (int off = 1; off < 256; off <<= 1) {
            int u = (t < 256 && t >= off) ? sc[t - off] : 0;
            __syncthreads();
            if (t < 256) sc[t] += u;
            __syncthreads();
        }
        int mybase = (b > 0) ? sc[b - 1] : 0;
        int cnt = bc[b];
        __syncthreads();                 // sc about to be reused

        // load my staged records, count per-node degrees
        uint2 rec[6];
        int nit = (cnt + 1023) >> 10;
        for (int i = 0; i < nit; ++i) {
            int idx = i * 1024 + t;
            if (idx < cnt) {
                rec[i] = staging[(size_t)b * BCAP + idx];
                atomicAdd(&dcnt[(rec[i].x >> 16) & 255], 1);
            }
        }
        __syncthreads();
        if (t < 256) sc[t] = dcnt[t];
        __syncthreads();
        #pragma unroll
        for (int off = 1; off < 256; off <<= 1) {
            int u = (t < 256 && t >= off) ? sc[t - off] : 0;
            __syncthreads();
            if (t < 256) sc[t] += u;
            __syncthreads();
        }
        if (t < 256) {
            int node = b * 256 + t;
            int excl = sc[t] - dcnt[t];
            if (node < N_NODES) offsets[node] = mybase + excl;
            dcnt[t] = mybase + excl;     // repurpose: global write cursor
        }
        if (b == NBUCK - 1 && t == 0) offsets[N_NODES] = mybase + cnt;
        __syncthreads();
        for (int i = 0; i < nit; ++i) {
            int idx = i * 1024 + t;
            if (idx < cnt) {
                int dl = (rec[i].x >> 16) & 255;
                int pos = atomicAdd(&dcnt[dl], 1);
                uint2 fin;
                fin.x = rec[i].x & 0xFFFFu;     // src
                fin.y = rec[i].y;               // w bits
                edges[pos] = fin;
            }
        }
    }
}

// ========== K3fused v2: per-node max + output GEMM, 1 node per WAVE =========
// R1 post-mortem: v1 (4 waves/block, 4 nodes SERIAL per wave) starved the
// latency-bound gather of TLP — 12,500 waves, Occupancy 33%, all pipes idle,
// 70 µs. Fix: block = 1024 thr = 16 waves = 16 nodes, ONE node per wave —
// identical per-wave dependence structure to the verified 162.7 µs K3
// (50,000 waves total). Grid 3125 blocks (exact).
//   gather (all 16 waves): old K3 loop verbatim, row -> swizzled LDS tile.
//   waves 0-7 then compute ONE 16-col block each of the output tile:
//     featb@Wn1 half issued BEFORE the barrier (global operands only —
//     absorbs intra-block gather imbalance), nsh@Wn2 half after.
//   waves 8-15 exit at the barrier and free their slots.
// Still eliminates the neighb round-trip (25.6 MB) and one launch boundary.
__global__ __launch_bounds__(1024) void fused_max_out(
    const unsigned short* __restrict__ featb,
    const unsigned short* __restrict__ hb,
    const int* __restrict__ offsets,
    const uint2* __restrict__ edges,
    const unsigned short* __restrict__ Wn1_f,
    const unsigned short* __restrict__ Wn2_f,
    const float* __restrict__ bias,
    float* __restrict__ out)
{
    __shared__ __align__(16) unsigned short nsh[16 * DF];   // swizzled 16x128 bf16
    const int t = threadIdx.x;
    const int lane = t & 63;
    const int wid = t >> 6;          // 0..15 == row within tile
    const int m0 = blockIdx.x * 16;
    const int half = lane >> 5;      // 0: even edge of pair, 1: odd edge
    const int q = lane & 31;         // column quarter: cols 4q..4q+3

    const int node = __builtin_amdgcn_readfirstlane(m0 + wid);
    int beg = offsets[node], end = offsets[node + 1];
    float4 mx = make_float4(-3.4e38f, -3.4e38f, -3.4e38f, -3.4e38f);

    for (int e = beg; e < end; e += 8) {
        int i1 = min(e + 1, end - 1);
        int i2 = min(e + 2, end - 1);
        int i3 = min(e + 3, end - 1);
        int i4 = min(e + 4, end - 1);
        int i5 = min(e + 5, end - 1);
        int i6 = min(e + 6, end - 1);
        int i7 = min(e + 7, end - 1);
        uint2 e0 = edges[e],  e1 = edges[i1], e2 = edges[i2], e3 = edges[i3];
        uint2 e4 = edges[i4], e5 = edges[i5], e6 = edges[i6], e7 = edges[i7];
        uint2 mA = half ? e1 : e0;
        uint2 mB = half ? e3 : e2;
        uint2 mC = half ? e5 : e4;
        uint2 mD = half ? e7 : e6;
        float wA = __uint_as_float(mA.y);
        float wB = __uint_as_float(mB.y);
        float wC = __uint_as_float(mC.y);
        float wD = __uint_as_float(mD.y);
        uint2 pA = *(const uint2*)(hb + (size_t)mA.x * DF + q * 4);
        uint2 pB = *(const uint2*)(hb + (size_t)mB.x * DF + q * 4);
        uint2 pC = *(const uint2*)(hb + (size_t)mC.x * DF + q * 4);
        uint2 pD = *(const uint2*)(hb + (size_t)mD.x * DF + q * 4);
        mx.x = fmaxf(mx.x, __uint_as_float(pA.x << 16)          * wA);
        mx.y = fmaxf(mx.y, __uint_as_float(pA.x & 0xffff0000u)  * wA);
        mx.z = fmaxf(mx.z, __uint_as_float(pA.y << 16)          * wA);
        mx.w = fmaxf(mx.w, __uint_as_float(pA.y & 0xffff0000u)  * wA);
        mx.x = fmaxf(mx.x, __uint_as_float(pB.x << 16)          * wB);
        mx.y = fmaxf(mx.y, __uint_as_float(pB.x & 0xffff0000u)  * wB);
        mx.z = fmaxf(mx.z, __uint_as_float(pB.y << 16)          * wB);
        mx.w = fmaxf(mx.w, __uint_as_float(pB.y & 0xffff0000u)  * wB);
        mx.x = fmaxf(mx.x, __uint_as_float(pC.x << 16)          * wC);
        mx.y = fmaxf(mx.y, __uint_as_float(pC.x & 0xffff0000u)  * wC);
        mx.z = fmaxf(mx.z, __uint_as_float(pC.y << 16)          * wC);
        mx.w = fmaxf(mx.w, __uint_as_float(pC.y & 0xffff0000u)  * wC);
        mx.x = fmaxf(mx.x, __uint_as_float(pD.x << 16)          * wD);
        mx.y = fmaxf(mx.y, __uint_as_float(pD.x & 0xffff0000u)  * wD);
        mx.z = fmaxf(mx.z, __uint_as_float(pD.y << 16)          * wD);
        mx.w = fmaxf(mx.w, __uint_as_float(pD.y & 0xffff0000u)  * wD);
    }

    float4 o;
    o.x = fmaxf(mx.x, __shfl_xor(mx.x, 32));
    o.y = fmaxf(mx.y, __shfl_xor(mx.y, 32));
    o.z = fmaxf(mx.z, __shfl_xor(mx.z, 32));
    o.w = fmaxf(mx.w, __shfl_xor(mx.w, 32));
    if (beg == end) o = make_float4(0.f, 0.f, 0.f, 0.f);
    if (half == 0) {
        ushort4 ob;
        ob.x = f2bf(o.x); ob.y = f2bf(o.y); ob.z = f2bf(o.z); ob.w = f2bf(o.w);
        int boff = wid * 256 + ((q * 8) ^ ((wid & 7) << 4));   // 8B-aligned
        *(ushort4*)((char*)nsh + boff) = ob;
    }

    // -------- phase 2: waves 0-7 each compute one 16-col block --------------
    const int n = lane & 15, quad = lane >> 4;
    f32x4 acc;
    if (wid < 8) {
        const int c = wid;
        float bv = bias[c * 16 + n];
        acc = (f32x4){bv, bv, bv, bv};
        const unsigned short* a0 = featb + (size_t)(m0 + n) * DF + quad * 8;
        #pragma unroll
        for (int tt = 0; tt < 4; ++tt) {
            bf16x8 af = *(const bf16x8*)(a0 + tt * 32);
            bf16x8 bfv = *(const bf16x8*)(Wn1_f + (size_t)((c * 4 + tt) * 64 + lane) * 8);
            acc = __builtin_amdgcn_mfma_f32_16x16x32_bf16(af, bfv, acc, 0, 0, 0);
        }
    }

    __syncthreads();                     // nsh fully written by all waves
    if (wid >= 8) return;                // free slots; waves 0-7 finish tile

    const int c = wid;
    #pragma unroll
    for (int tt = 0; tt < 4; ++tt) {
        int boff = (quad * 16 + tt * 64) ^ ((n & 7) << 4);         // 16B-aligned
        bf16x8 af = *(const bf16x8*)((const char*)nsh + n * 256 + boff);
        bf16x8 bfv = *(const bf16x8*)(Wn2_f + (size_t)((c * 4 + tt) * 64 + lane) * 8);
        acc = __builtin_amdgcn_mfma_f32_16x16x32_bf16(af, bfv, acc, 0, 0, 0);
    }

    #pragma unroll
    for (int r = 0; r < 4; ++r)
        out[(size_t)(m0 + quad * 4 + r) * DF + c * 16 + n] = acc[r];
}

extern "C" void kernel_launch(void* const* d_in, const int* in_sizes, int n_in,
                              void* d_out, int out_size, void* d_ws, size_t ws_size,
                              hipStream_t stream) {
    const float* feat    = (const float*)d_in[0];
    const float* weight  = (const float*)d_in[1];
    const int*   src     = (const int*)d_in[2];
    const int*   dst     = (const int*)d_in[3];
    const float* W_pool  = (const float*)d_in[4];
    const float* b_pool  = (const float*)d_in[5];
    const float* W_neigh = (const float*)d_in[6];
    const float* b_neigh = (const float*)d_in[7];
    float* out = (float*)d_out;

    char* ws = (char*)d_ws;
    unsigned short* featb  = (unsigned short*)(ws);              // 12,800,000 B
    unsigned short* hb     = (unsigned short*)(ws + 12800000);   // 12,800,000 B
    // (ws + 25600000 .. 38400000 formerly neighb — now unused after K3/K4 fusion)
    unsigned short* Wp_f   = (unsigned short*)(ws + 38400000);   // 32,768 B
    unsigned short* Wn1_f  = (unsigned short*)(ws + 38432768);   // 32,768 B
    unsigned short* Wn2_f  = (unsigned short*)(ws + 38465536);   // 32,768 B
    int*   offsets   = (int*)  (ws + 38498304);                  // 200,064 B
    int*   bucketcnt = (int*)  (ws + 38698368);                  // 1,024 B
    uint2* staging   = (uint2*)(ws + 38699392);                  // 9,633,792 B
    uint2* edges     = (uint2*)(ws + 48333184);                  // 5,120,000 B -> ~53.5 MB

    hipMemsetAsync(bucketcnt, 0, 1024, stream);

    // K1: PassA (coarse bucket scatter) || featb conversion || W fragments
    const int K1_BLOCKS = PA_BLOCKS + NF4 / 256 + NWG / 256;   // 250+6250+24
    k1_setup_bucket<<<K1_BLOCKS, 256, 0, stream>>>(
        feat, W_pool, W_neigh, src, dst, weight,
        featb, Wp_f, Wn1_f, Wn2_f, bucketcnt, staging);

    // K2: gemm_pool (hb) || PassB (offsets + final dst-sorted edges)
    k2_gemm_passb<<<GEMMB + NBUCK, 1024, 0, stream>>>(
        featb, Wp_f, b_pool, hb, bucketcnt, staging, offsets, edges);

    // K3fused: segment-max gather (1 node/wave) + out GEMM
    fused_max_out<<<N_NODES / 16, 1024, 0, stream>>>(
        featb, hb, offsets, edges, Wn1_f, Wn2_f, b_neigh, out);
}